// Round 6
// baseline (4589.270 us; speedup 1.0000x reference)
//
#include <hip/hip_runtime.h>
#include <math.h>

typedef unsigned long long u64;

#define S_LEN 1024
#define E_DIM 512
#define H_DIM 512
#define G3    1536   // 3*H
#define D_DIM 1024

#define NCHAIN 4
#define WPC    32    // workgroups per GRU chain (128 blocks total, co-resident on 256 CUs)

// ---------------------------------------------------------------------------
// Fast gate math (verified round 5: passed, absmax 0.0).
// sigmoid via v_exp_f32 + v_rcp_f32; tanh(x) = 1 - 2/(1+e^{2x}).
// Saturation-correct at +/-inf.
// ---------------------------------------------------------------------------
__device__ __forceinline__ float fast_sigmoid(float x) {
    return __builtin_amdgcn_rcpf(1.f + __expf(-x));
}
__device__ __forceinline__ float fast_tanh(float x) {
    return 1.f - 2.f * __builtin_amdgcn_rcpf(1.f + __expf(2.f * x));
}
__device__ __forceinline__ float dot4(float4 a, float4 b, float acc) {
    acc = fmaf(a.x, b.x, acc);
    acc = fmaf(a.y, b.y, acc);
    acc = fmaf(a.z, b.z, acc);
    acc = fmaf(a.w, b.w, acc);
    return acc;
}

// ---------------------------------------------------------------------------
// FUSED scan: phase-1 (gi = x@Wih.T + bih) is folded into the recurrence.
// The Wih@x partial dot runs INSIDE the poll loop (the scan is ~75% poll-wait
// at 4630 cy/step, round-5 counters), so its cost hides under the exchange
// round trip, and the separate ~250 us gi GEMM kernel is deleted.
//
// Exchange protocol = round-0/4/5 VERIFIED scheme, exactly: hpk[c][parity][i]
// is a 64-bit slot {tag:u32 = step, val:f32}; relaxed agent-scope atomic
// store/load; tag rides with the value -> fence-free; parity double-buffer +
// exact-tag match; 0xAA poison never matches; monotone tags -> replay-safe.
//
// Compute core = verified lane-group structure: wave wv owns outputs
// base_i..base_i+3; 16-lane group q computes output base_i+q; lane r covers
// cols {4r+64k+e}. LDS reads are group-broadcast float4s (bank-conflict
// counter = 0 in rounds 3-5). Reduce via __shfl_down(...,16) down-shift
// tree into lane r=0 (verified round 5).
//
// GRU numerics: n-gate needs gi_n and gh_n separate (n = tanh(gi_n + r*gh_n)),
// so the reduce carries 4 accumulators: r_ih+r_hh, z_ih+z_hh, n_ih, n_hh.
//
// Embedding row x_t (2 KB) is double-buffered in LDS: the next row's global
// loads are issued right after the poll (latency hides under the h-matvec),
// written to LDS after publish, sealed by a second __syncthreads.
// ---------------------------------------------------------------------------
__global__ __launch_bounds__(256, 1) void gru_scan_fused_kernel(
    const int* __restrict__ sent, const float* __restrict__ emb,
    const float* __restrict__ Wih0, const float* __restrict__ Whh0,
    const float* __restrict__ bih0, const float* __restrict__ bhh0,
    const float* __restrict__ Wih1, const float* __restrict__ Whh1,
    const float* __restrict__ bih1, const float* __restrict__ bhh1,
    const float* __restrict__ Wih2, const float* __restrict__ Whh2,
    const float* __restrict__ bih2, const float* __restrict__ bhh2,
    const float* __restrict__ Wih3, const float* __restrict__ Whh3,
    const float* __restrict__ bih3, const float* __restrict__ bhh3,
    u64* __restrict__ hpk)             // [4][2][512] {tag,val} slots
{
    __shared__ float lds_h[2][H_DIM];
    __shared__ float lds_x[2][E_DIM];   // embedding-row double buffer

    int b = blockIdx.x;
    int c = b / WPC;
    int w = b % WPC;
    const float* Wih = (c==0)?Wih0:(c==1)?Wih1:(c==2)?Wih2:Wih3;
    const float* Whh = (c==0)?Whh0:(c==1)?Whh1:(c==2)?Whh2:Whh3;
    const float* bih = (c==0)?bih0:(c==1)?bih1:(c==2)?bih2:bih3;
    const float* bhh = (c==0)?bhh0:(c==1)?bhh1:(c==2)?bhh2:bhh3;
    u64* hp = hpk + (size_t)c * 2 * H_DIM;
    const bool fwd = ((c & 1) == 0);   // chains 0 (ctx_f) and 2 (qry_f) are forward

    int tid  = threadIdx.x;
    int wv   = tid >> 6;
    int lane = tid & 63;
    int q    = lane >> 4;      // lane-group = which of the wave's 4 outputs
    int r    = lane & 15;      // position within group
    int base_i = w * 16 + wv * 4;
    int my_i   = base_i + q;   // output index this group computes
    bool pub   = (r == 0);     // lanes 0,16,32,48 publish

    // Weight fragments in registers: row (g*512 + my_i), cols {4r+64k+e}.
    // whr = recurrent (Whh), wir = input (Wih). 192 floats/thread.
    float4 whr[3][8], wir[3][8];
    #pragma unroll
    for (int g = 0; g < 3; ++g) {
        const float* hrow = Whh + (size_t)(g * H_DIM + my_i) * H_DIM;
        const float* irow = Wih + (size_t)(g * H_DIM + my_i) * E_DIM;
        #pragma unroll
        for (int k = 0; k < 8; ++k) {
            whr[g][k] = *(const float4*)(hrow + 4 * r + 64 * k);
            wir[g][k] = *(const float4*)(irow + 4 * r + 64 * k);
        }
    }

    float bh_r=0.f, bh_z=0.f, bh_n=0.f;
    float bi_r=0.f, bi_z=0.f, bi_n=0.f;
    if (pub) {
        bh_r = bhh[my_i]; bh_z = bhh[H_DIM + my_i]; bh_n = bhh[2*H_DIM + my_i];
        bi_r = bih[my_i]; bi_z = bih[H_DIM + my_i]; bi_n = bih[2*H_DIM + my_i];
    }

    // h_0 = 0 lives in LDS buffer 0; embedding row for step 0 in lds_x[0].
    lds_h[0][tid]       = 0.f;
    lds_h[0][tid + 256] = 0.f;
    {
        int t0 = fwd ? 0 : (S_LEN - 1);
        int row0 = sent[t0];
        if (tid < 128)
            *(float4*)&lds_x[0][tid * 4] =
                *(const float4*)(emb + (size_t)row0 * E_DIM + tid * 4);
    }
    __syncthreads();

    // Each thread ferries slots tid and tid+256.
    int s0 = tid, s1 = tid + 256;
    bool own0 = ((s0 >> 4) == w);
    bool own1 = ((s1 >> 4) == w);

    for (int s = 0; s < S_LEN; ++s) {
        int pb = s & 1;
        const float* xb = &lds_x[pb][0];
        float ea0 = 0.f, ea1 = 0.f, ea2 = 0.f;   // Wih@x partials (3 gates)
        int ac = 0;

        if (s > 0) {
            // Direct self-tagged slot poll (verified), with the input-side
            // matvec interleaved into the load-latency shadow.
            const u64* srcp = hp + (size_t)pb * H_DIM;
            bool p0 = own0, p1 = own1;
            while (!(p0 && p1)) {
                u64 v0 = 0, v1 = 0;
                if (!p0) v0 = __hip_atomic_load(srcp + s0, __ATOMIC_RELAXED, __HIP_MEMORY_SCOPE_AGENT);
                if (!p1) v1 = __hip_atomic_load(srcp + s1, __ATOMIC_RELAXED, __HIP_MEMORY_SCOPE_AGENT);
                if (ac < 8) {   // one emb-part chunk while the loads fly
                    float4 xv = *(const float4*)(xb + 4 * r + 64 * ac);
                    ea0 = dot4(wir[0][ac], xv, ea0);
                    ea1 = dot4(wir[1][ac], xv, ea1);
                    ea2 = dot4(wir[2][ac], xv, ea2);
                    ++ac;
                }
                if (!p0 && (unsigned)(v0 >> 32) == (unsigned)s) {
                    lds_h[pb][s0] = __uint_as_float((unsigned)v0);
                    p0 = true;
                }
                if (!p1 && (unsigned)(v1 >> 32) == (unsigned)s) {
                    lds_h[pb][s1] = __uint_as_float((unsigned)v1);
                    p1 = true;
                }
            }
        }
        // Finish any remaining emb-part chunks (also the whole of step 0,
        // and the path taken by slot-owner threads that skip the poll).
        for (; ac < 8; ++ac) {
            float4 xv = *(const float4*)(xb + 4 * r + 64 * ac);
            ea0 = dot4(wir[0][ac], xv, ea0);
            ea1 = dot4(wir[1][ac], xv, ea1);
            ea2 = dot4(wir[2][ac], xv, ea2);
        }
        __syncthreads();

        // Issue next embedding-row loads NOW; written to LDS after publish,
        // so their latency hides under the h-matvec + reduce + gates.
        float4 xpre = make_float4(0.f, 0.f, 0.f, 0.f);
        bool do_pre = (tid < 128) && (s + 1 < S_LEN);
        if (do_pre) {
            int tn = fwd ? (s + 1) : (S_LEN - 2 - s);
            int rown = sent[tn];
            xpre = *(const float4*)(emb + (size_t)rown * E_DIM + tid * 4);
        }

        // hv read hoisted: LDS latency overlaps the matvec below.
        float hv = lds_h[pb][my_i];

        // Recurrent matvec: conflict-free broadcast float4 reads.
        float ha0 = 0.f, ha1 = 0.f, ha2 = 0.f;
        const float* hb = &lds_h[pb][0];
        #pragma unroll
        for (int k = 0; k < 8; ++k) {
            float4 hfv = *(const float4*)(hb + 4 * r + 64 * k);
            ha0 = dot4(whr[0][k], hfv, ha0);
            ha1 = dot4(whr[1][k], hfv, ha1);
            ha2 = dot4(whr[2][k], hfv, ha2);
        }

        // 4-accumulator reduce (n-gate keeps ih/hh parts separate).
        float red0 = ea0 + ha0;   // r-gate total
        float red1 = ea1 + ha1;   // z-gate total
        float red2 = ea2;         // n-gate input side
        float red3 = ha2;         // n-gate recurrent side
        #pragma unroll
        for (int off = 8; off >= 1; off >>= 1) {
            red0 += __shfl_down(red0, off, 16);
            red1 += __shfl_down(red1, off, 16);
            red2 += __shfl_down(red2, off, 16);
            red3 += __shfl_down(red3, off, 16);
        }

        if (pub) {
            float rr = fast_sigmoid(red0 + bi_r + bh_r);
            float zz = fast_sigmoid(red1 + bi_z + bh_z);
            float nn = fast_tanh((red2 + bi_n) + rr * (red3 + bh_n));
            float hn = (1.f - zz) * nn + zz * hv;
            // Own value short-circuits through LDS for this block...
            lds_h[pb ^ 1][my_i] = hn;
            // ...and is published device-wide with the step tag riding along.
            union { float f; unsigned u; } cv; cv.f = hn;
            u64 pk = ((u64)(unsigned)(s + 1) << 32) | (u64)cv.u;
            __hip_atomic_store(hp + (size_t)(pb ^ 1) * H_DIM + my_i, pk,
                               __ATOMIC_RELAXED, __HIP_MEMORY_SCOPE_AGENT);
        }
        // Land the prefetched embedding row; sealed by the barrier below.
        if (do_pre) *(float4*)&lds_x[pb ^ 1][tid * 4] = xpre;
        __syncthreads();
    }
}

// ---------------------------------------------------------------------------
// Phase 3a: h1 = relu(d1_w @ rep + d1_b); rep[j] = val(hpk[j>>9][0][j&511])
// (final h_1024 sits in parity-0 slots, tag 1024). One wave per output row.
// ---------------------------------------------------------------------------
__global__ __launch_bounds__(256) void dense1_kernel(
    const float* __restrict__ d1w, const float* __restrict__ d1b,
    const u64* __restrict__ hpk, float* __restrict__ h1)
{
    int wv = threadIdx.x >> 6, lane = threadIdx.x & 63;
    int row = blockIdx.x * 4 + wv;
    const float* wr = d1w + (size_t)row * (4 * H_DIM);
    float sum = 0.f;
    #pragma unroll
    for (int q = 0; q < 32; ++q) {
        int j = lane + q * 64;
        int cc = j >> 9;
        float h = __uint_as_float((unsigned)hpk[(size_t)cc * 2 * H_DIM + (j & 511)]);
        sum = fmaf(wr[j], h, sum);
    }
    #pragma unroll
    for (int off = 32; off >= 1; off >>= 1) sum += __shfl_xor(sum, off, 64);
    if (lane == 0) h1[row] = fmaxf(sum + d1b[row], 0.f);
}

// Phase 3b: out = sigmoid(d2_w @ h1 + d2_b), one block.
__global__ __launch_bounds__(256) void dense2_kernel(
    const float* __restrict__ d2w, const float* __restrict__ d2b,
    const float* __restrict__ h1, float* __restrict__ out)
{
    __shared__ float red[4];
    int tid = threadIdx.x, lane = tid & 63, wv = tid >> 6;
    float sum = 0.f;
    #pragma unroll
    for (int q = 0; q < 4; ++q) { int j = tid + q * 256; sum = fmaf(d2w[j], h1[j], sum); }
    #pragma unroll
    for (int off = 32; off >= 1; off >>= 1) sum += __shfl_xor(sum, off, 64);
    if (lane == 0) red[wv] = sum;
    __syncthreads();
    if (tid == 0) {
        float t = red[0] + red[1] + red[2] + red[3] + d2b[0];
        out[0] = 1.f / (1.f + expf(-t));
    }
}

// ---------------------------------------------------------------------------
extern "C" void kernel_launch(void* const* d_in, const int* in_sizes, int n_in,
                              void* d_out, int out_size, void* d_ws, size_t ws_size,
                              hipStream_t stream) {
    const int*   sent = (const int*)d_in[0];
    const float* emb  = (const float*)d_in[1];
    const float* Wih[4], *Whh[4], *bih[4], *bhh[4];
    for (int p = 0; p < 4; ++p) {
        Wih[p] = (const float*)d_in[2 + 4*p + 0];
        Whh[p] = (const float*)d_in[2 + 4*p + 1];
        bih[p] = (const float*)d_in[2 + 4*p + 2];
        bhh[p] = (const float*)d_in[2 + 4*p + 3];
    }
    const float* d1w = (const float*)d_in[18];
    const float* d1b = (const float*)d_in[19];
    const float* d2w = (const float*)d_in[20];
    const float* d2b = (const float*)d_in[21];
    float* out = (float*)d_out;

    // Workspace layout (gi region retained for offset compatibility; unused):
    //   gi    : 4*1024*1536 floats = 25165824 B   (UNUSED after fusion)
    //   hpk   : 4*2*512 u64        = 32768 B      (self-tagged; no init needed,
    //                                              0xAA poison never matches a tag)
    //   h1    : 1024 floats        = 4096 B
    u64*   hpk = (u64*)((char*)d_ws + (size_t)NCHAIN * S_LEN * G3 * sizeof(float));
    float* h1  = (float*)((char*)hpk + (size_t)NCHAIN * 2 * H_DIM * sizeof(u64));

    gru_scan_fused_kernel<<<NCHAIN * WPC, 256, 0, stream>>>(
        sent, emb,
        Wih[0], Whh[0], bih[0], bhh[0],
        Wih[1], Whh[1], bih[1], bhh[1],
        Wih[2], Whh[2], bih[2], bhh[2],
        Wih[3], Whh[3], bih[3], bhh[3],
        hpk);

    dense1_kernel<<<D_DIM / 4, 256, 0, stream>>>(d1w, d1b, hpk, h1);
    dense2_kernel<<<1, 256, 0, stream>>>(d2w, d2b, h1, out);
}

// Round 7
// 2742.376 us; speedup vs baseline: 1.6735x; 1.6735x over previous
//
#include <hip/hip_runtime.h>
#include <math.h>

typedef unsigned long long u64;

#define S_LEN 1024
#define E_DIM 512
#define H_DIM 512
#define G3    1536   // 3*H
#define D_DIM 1024

#define NCHAIN 4
#define WPC    32    // workgroups per GRU chain (128 blocks total, co-resident on 256 CUs)

// ---------------------------------------------------------------------------
// Phase 1: gi[p][t][j] = bih_p[j] + sum_k emb[sent[t],k] * Wih_p[j,k]
// Retiled fp32 GEMM: 128x128 tile, BK=16, 256 threads, 8x8 micro-tile
// (arranged as 4+4 split so LDS reads keep the verified stride-4 pattern:
// <=2-way bank aliasing = free). Summation order over k is sequential,
// identical to the round-0..5 kernel -> bitwise-identical gi.
// ---------------------------------------------------------------------------
#define TMG 128
#define TNG 128
#define BKG 16

__global__ __launch_bounds__(256) void gi_gemm_kernel(
    const int* __restrict__ sent, const float* __restrict__ emb,
    const float* __restrict__ Wih0, const float* __restrict__ bih0,
    const float* __restrict__ Wih1, const float* __restrict__ bih1,
    const float* __restrict__ Wih2, const float* __restrict__ bih2,
    const float* __restrict__ Wih3, const float* __restrict__ bih3,
    float* __restrict__ gi)
{
    __shared__ float As[BKG][TMG + 1];
    __shared__ float Bs[BKG][TNG + 1];
    __shared__ int   rows[TMG];

    const int blocks_t = S_LEN / TMG;   // 8
    const int blocks_j = G3 / TNG;      // 12
    int b   = blockIdx.x;
    int p   = b / (blocks_t * blocks_j);
    int rem = b % (blocks_t * blocks_j);
    int bt  = rem / blocks_j;
    int bj  = rem % blocks_j;

    const float* Wih = (p == 0) ? Wih0 : (p == 1) ? Wih1 : (p == 2) ? Wih2 : Wih3;
    const float* bih = (p == 0) ? bih0 : (p == 1) ? bih1 : (p == 2) ? bih2 : bih3;

    int tid = threadIdx.x;
    if (tid < TMG) rows[tid] = sent[bt * TMG + tid];
    __syncthreads();

    int tt4 = (tid >> 4) * 4;   // 0..60 : row micro-offset (plus +64 twin)
    int jj4 = (tid & 15) * 4;   // 0..60 : col micro-offset (plus +64 twin)
    float acc[8][8] = {{0.f}};

    int lr = tid >> 1;          // 0..127 (row within tile)
    int lc = (tid & 1) * 8;     // 0 or 8 (k chunk)

    for (int k0 = 0; k0 < E_DIM; k0 += BKG) {
        const float* asrc = emb + (size_t)rows[lr] * E_DIM + (k0 + lc);
        float4 a0 = *(const float4*)asrc;
        float4 a1 = *(const float4*)(asrc + 4);
        const float* bsrc = Wih + (size_t)(bj * TNG + lr) * E_DIM + (k0 + lc);
        float4 b0 = *(const float4*)bsrc;
        float4 b1 = *(const float4*)(bsrc + 4);

        As[lc+0][lr]=a0.x; As[lc+1][lr]=a0.y; As[lc+2][lr]=a0.z; As[lc+3][lr]=a0.w;
        As[lc+4][lr]=a1.x; As[lc+5][lr]=a1.y; As[lc+6][lr]=a1.z; As[lc+7][lr]=a1.w;
        Bs[lc+0][lr]=b0.x; Bs[lc+1][lr]=b0.y; Bs[lc+2][lr]=b0.z; Bs[lc+3][lr]=b0.w;
        Bs[lc+4][lr]=b1.x; Bs[lc+5][lr]=b1.y; Bs[lc+6][lr]=b1.z; Bs[lc+7][lr]=b1.w;
        __syncthreads();

        #pragma unroll
        for (int kk = 0; kk < BKG; ++kk) {
            float av[8], bv[8];
            #pragma unroll
            for (int e = 0; e < 4; ++e) {
                av[e]   = As[kk][tt4 + e];
                av[4+e] = As[kk][64 + tt4 + e];
                bv[e]   = Bs[kk][jj4 + e];
                bv[4+e] = Bs[kk][64 + jj4 + e];
            }
            #pragma unroll
            for (int i = 0; i < 8; ++i)
                #pragma unroll
                for (int j2 = 0; j2 < 8; ++j2)
                    acc[i][j2] = fmaf(av[i], bv[j2], acc[i][j2]);
        }
        __syncthreads();
    }

    float* gout = gi + (size_t)p * S_LEN * G3;
    int jb0 = bj * TNG + jj4;        // cols jb0..jb0+3
    int jb1 = jb0 + 64;              // cols jb1..jb1+3
    float c00 = bih[jb0+0], c01 = bih[jb0+1], c02 = bih[jb0+2], c03 = bih[jb0+3];
    float c10 = bih[jb1+0], c11 = bih[jb1+1], c12 = bih[jb1+2], c13 = bih[jb1+3];
    #pragma unroll
    for (int i = 0; i < 8; ++i) {
        int t = bt * TMG + ((i < 4) ? (tt4 + i) : (64 + tt4 + (i - 4)));
        float4 v0 = make_float4(acc[i][0]+c00, acc[i][1]+c01, acc[i][2]+c02, acc[i][3]+c03);
        float4 v1 = make_float4(acc[i][4]+c10, acc[i][5]+c11, acc[i][6]+c12, acc[i][7]+c13);
        *(float4*)(gout + (size_t)t * G3 + jb0) = v0;
        *(float4*)(gout + (size_t)t * G3 + jb1) = v1;
    }
}

// ---------------------------------------------------------------------------
// Fast gate math (verified round 5: passed, absmax 0.0).
// ---------------------------------------------------------------------------
__device__ __forceinline__ float fast_sigmoid(float x) {
    return __builtin_amdgcn_rcpf(1.f + __expf(-x));
}
__device__ __forceinline__ float fast_tanh(float x) {
    return 1.f - 2.f * __builtin_amdgcn_rcpf(1.f + __expf(2.f * x));
}

// ---------------------------------------------------------------------------
// Phase 2: 4 independent GRU recurrences — round-5 VERIFIED kernel, with ONE
// change: exchange slots are STRIDED by `ss` u64s (ss chosen on host from
// ws_size; ss=1 reproduces round-5 exactly). Rationale: the dense layout put
// each chain's whole parity buffer in 4 KB of contiguous address space ->
// likely 1-2 memory channels / LLC slices absorb ALL poll+publish traffic
// from 32k threads. Striding spreads the 512 slots across channels.
// Protocol (self-tagged {tag:u32=step, val:f32} u64 slots, relaxed
// agent-scope atomics, parity double-buffer, exact-tag match) is unchanged.
// ---------------------------------------------------------------------------
__global__ __launch_bounds__(256, 1) void gru_scan_kernel(
    const float* __restrict__ Whh0, const float* __restrict__ bhh0,
    const float* __restrict__ Whh1, const float* __restrict__ bhh1,
    const float* __restrict__ Whh2, const float* __restrict__ bhh2,
    const float* __restrict__ Whh3, const float* __restrict__ bhh3,
    const float* __restrict__ gi,
    u64* __restrict__ hpk,             // [4][2][512*ss] strided {tag,val} slots
    int ss)
{
    __shared__ float lds_h[2][H_DIM];

    int b = blockIdx.x;
    int c = b / WPC;
    int w = b % WPC;
    const float* Whh = (c==0)?Whh0:(c==1)?Whh1:(c==2)?Whh2:Whh3;
    const float* bhh = (c==0)?bhh0:(c==1)?bhh1:(c==2)?bhh2:bhh3;
    const float* gic = gi + (size_t)c * S_LEN * G3;
    u64* hp = hpk + (size_t)c * 2 * H_DIM * ss;
    const size_t par = (size_t)H_DIM * ss;     // parity offset in u64s
    const bool fwd = ((c & 1) == 0);   // chains 0 (ctx_f) and 2 (qry_f) are forward

    int tid  = threadIdx.x;
    int wv   = tid >> 6;
    int lane = tid & 63;
    int q    = lane >> 4;      // lane-group = which of the wave's 4 outputs
    int r    = lane & 15;      // position within group
    int base_i = w * 16 + wv * 4;
    int my_i   = base_i + q;   // output index this group computes
    bool pub   = (r == 0);     // lanes 0,16,32,48 publish

    // Weights: group q needs row (g*512 + my_i); lane r covers columns
    // {4r + 64k + e : k=0..7, e=0..3} as 8 float4s. 96 floats/thread.
    float4 wregv[3][8];
    #pragma unroll
    for (int g = 0; g < 3; ++g) {
        const float* rowp = Whh + (size_t)(g * H_DIM + my_i) * H_DIM;
        #pragma unroll
        for (int k = 0; k < 8; ++k)
            wregv[g][k] = *(const float4*)(rowp + 4 * r + 64 * k);
    }

    float bh_r=0.f, bh_z=0.f, bh_n=0.f;
    float gr=0.f, gz=0.f, gn=0.f;
    if (pub) {
        bh_r = bhh[my_i]; bh_z = bhh[H_DIM + my_i]; bh_n = bhh[2*H_DIM + my_i];
        int t0 = fwd ? 0 : (S_LEN - 1);
        const float* g0 = gic + (size_t)t0 * G3;
        gr = g0[my_i]; gz = g0[H_DIM + my_i]; gn = g0[2*H_DIM + my_i];
    }

    // h_0 = 0 lives in LDS buffer 0.
    lds_h[0][tid]       = 0.f;
    lds_h[0][tid + 256] = 0.f;

    // Each thread ferries slots tid and tid+256 (strided addresses).
    int s0 = tid, s1 = tid + 256;
    bool own0 = ((s0 >> 4) == w);
    bool own1 = ((s1 >> 4) == w);
    u64* slotA = hp + (size_t)s0 * ss;
    u64* slotB = hp + (size_t)s1 * ss;
    u64* pubp  = hp + (size_t)my_i * ss;   // meaningful for pub lanes

    for (int s = 0; s < S_LEN; ++s) {
        int pb = s & 1;
        size_t poff = pb ? par : 0;
        if (s > 0) {
            // Direct self-tagged slot poll (verified; slots become ready
            // incrementally and are ferried to LDS as they land).
            bool p0 = own0, p1 = own1;
            while (!(p0 && p1)) {
                if (!p0) {
                    u64 v = __hip_atomic_load(slotA + poff, __ATOMIC_RELAXED, __HIP_MEMORY_SCOPE_AGENT);
                    if ((unsigned)(v >> 32) == (unsigned)s) {
                        lds_h[pb][s0] = __uint_as_float((unsigned)v);
                        p0 = true;
                    }
                }
                if (!p1) {
                    u64 v = __hip_atomic_load(slotB + poff, __ATOMIC_RELAXED, __HIP_MEMORY_SCOPE_AGENT);
                    if ((unsigned)(v >> 32) == (unsigned)s) {
                        lds_h[pb][s1] = __uint_as_float((unsigned)v);
                        p1 = true;
                    }
                }
            }
        }
        __syncthreads();

        // Early gi prefetch: issued before the matvec so its HBM latency
        // overlaps compute AND the next poll wait. NOT drained here.
        float ngr = 0.f, ngz = 0.f, ngn = 0.f;
        if (pub && s + 1 < S_LEN) {
            int tn = fwd ? (s + 1) : (S_LEN - 2 - s);
            const float* gnx = gic + (size_t)tn * G3;
            ngr = gnx[my_i]; ngz = gnx[H_DIM + my_i]; ngn = gnx[2*H_DIM + my_i];
        }

        // hv read hoisted: LDS latency overlaps the matvec below.
        float hv = lds_h[pb][my_i];

        // hf: 8 float4 reads, conflict-free (bank-conflict = 0, rounds 3-5).
        float4 hfv[8];
        const float* hbase = &lds_h[pb][0];
        #pragma unroll
        for (int k = 0; k < 8; ++k)
            hfv[k] = *(const float4*)(hbase + 4 * r + 64 * k);

        float acc[3];
        #pragma unroll
        for (int g = 0; g < 3; ++g) {
            float a = 0.f;
            #pragma unroll
            for (int k = 0; k < 8; ++k) {
                a = fmaf(wregv[g][k].x, hfv[k].x, a);
                a = fmaf(wregv[g][k].y, hfv[k].y, a);
                a = fmaf(wregv[g][k].z, hfv[k].z, a);
                a = fmaf(wregv[g][k].w, hfv[k].w, a);
            }
            acc[g] = a;
        }
        // Reduce within the 16-lane group via down-shifts into lane r=0
        // (the publisher) — verified round 5.
        #pragma unroll
        for (int off = 8; off >= 1; off >>= 1)
            #pragma unroll
            for (int g = 0; g < 3; ++g)
                acc[g] += __shfl_down(acc[g], off, 16);

        if (pub) {
            float rr = fast_sigmoid(gr + acc[0] + bh_r);
            float zz = fast_sigmoid(gz + acc[1] + bh_z);
            float nn = fast_tanh(gn + rr * (acc[2] + bh_n));
            float hn = (1.f - zz) * nn + zz * hv;
            // Own value short-circuits through LDS for this block...
            lds_h[pb ^ 1][my_i] = hn;
            // ...and is published device-wide with the step tag riding along.
            union { float f; unsigned u; } cv; cv.f = hn;
            u64 pk = ((u64)(unsigned)(s + 1) << 32) | (u64)cv.u;
            __hip_atomic_store(pubp + (pb ? 0 : par), pk,
                               __ATOMIC_RELAXED, __HIP_MEMORY_SCOPE_AGENT);
            // Rotate in the prefetched gi values for the next step.
            gr = ngr; gz = ngz; gn = ngn;
        }
    }
}

// ---------------------------------------------------------------------------
// Phase 3a: h1 = relu(d1_w @ rep + d1_b); rep[j] = val of strided slot
// (j>>9 chain, parity 0, index j&511). One wave per output row.
// ---------------------------------------------------------------------------
__global__ __launch_bounds__(256) void dense1_kernel(
    const float* __restrict__ d1w, const float* __restrict__ d1b,
    const u64* __restrict__ hpk, float* __restrict__ h1, int ss)
{
    int wv = threadIdx.x >> 6, lane = threadIdx.x & 63;
    int row = blockIdx.x * 4 + wv;
    const float* wr = d1w + (size_t)row * (4 * H_DIM);
    float sum = 0.f;
    #pragma unroll
    for (int q = 0; q < 32; ++q) {
        int j = lane + q * 64;
        int cc = j >> 9;
        u64 v = hpk[((size_t)cc * 2 * H_DIM + (j & 511)) * ss];
        float h = __uint_as_float((unsigned)v);
        sum = fmaf(wr[j], h, sum);
    }
    #pragma unroll
    for (int off = 32; off >= 1; off >>= 1) sum += __shfl_xor(sum, off, 64);
    if (lane == 0) h1[row] = fmaxf(sum + d1b[row], 0.f);
}

// Phase 3b: out = sigmoid(d2_w @ h1 + d2_b), one block.
__global__ __launch_bounds__(256) void dense2_kernel(
    const float* __restrict__ d2w, const float* __restrict__ d2b,
    const float* __restrict__ h1, float* __restrict__ out)
{
    __shared__ float red[4];
    int tid = threadIdx.x, lane = tid & 63, wv = tid >> 6;
    float sum = 0.f;
    #pragma unroll
    for (int q = 0; q < 4; ++q) { int j = tid + q * 256; sum = fmaf(d2w[j], h1[j], sum); }
    #pragma unroll
    for (int off = 32; off >= 1; off >>= 1) sum += __shfl_xor(sum, off, 64);
    if (lane == 0) red[wv] = sum;
    __syncthreads();
    if (tid == 0) {
        float t = red[0] + red[1] + red[2] + red[3] + d2b[0];
        out[0] = 1.f / (1.f + expf(-t));
    }
}

// ---------------------------------------------------------------------------
extern "C" void kernel_launch(void* const* d_in, const int* in_sizes, int n_in,
                              void* d_out, int out_size, void* d_ws, size_t ws_size,
                              hipStream_t stream) {
    const int*   sent = (const int*)d_in[0];
    const float* emb  = (const float*)d_in[1];
    const float* Wih[4], *Whh[4], *bih[4], *bhh[4];
    for (int p = 0; p < 4; ++p) {
        Wih[p] = (const float*)d_in[2 + 4*p + 0];
        Whh[p] = (const float*)d_in[2 + 4*p + 1];
        bih[p] = (const float*)d_in[2 + 4*p + 2];
        bhh[p] = (const float*)d_in[2 + 4*p + 3];
    }
    const float* d1w = (const float*)d_in[18];
    const float* d1b = (const float*)d_in[19];
    const float* d2w = (const float*)d_in[20];
    const float* d2b = (const float*)d_in[21];
    float* out = (float*)d_out;

    // Workspace layout:
    //   gi  : 4*1024*1536 floats = 25165824 B
    //   h1  : 1024 floats        = 4096 B
    //   hpk : 4*2*512*ss u64     = 32768*ss B  (strided self-tagged slots;
    //         ss = largest power-of-2 stride (<=32, i.e. 256B lines) that
    //         fits in the remaining workspace; ss=1 == verified round-5
    //         dense layout, so this degrades safely if ws is tight)
    size_t gi_bytes = (size_t)NCHAIN * S_LEN * G3 * sizeof(float);
    size_t h1_bytes = (size_t)D_DIM * sizeof(float);
    size_t base = gi_bytes + h1_bytes;          // both 256B-aligned already
    size_t avail = (ws_size > base) ? (ws_size - base) : 0;
    int ss = 1;
    while (ss < 32 && (size_t)NCHAIN * 2 * H_DIM * (size_t)(ss * 2) * sizeof(u64) <= avail)
        ss *= 2;

    float* gi  = (float*)d_ws;
    float* h1  = (float*)((char*)d_ws + gi_bytes);
    u64*   hpk = (u64*)((char*)d_ws + base);

    gi_gemm_kernel<<<NCHAIN * (S_LEN/TMG) * (G3/TNG), 256, 0, stream>>>(
        sent, emb,
        Wih[0], bih[0], Wih[1], bih[1], Wih[2], bih[2], Wih[3], bih[3], gi);

    gru_scan_kernel<<<NCHAIN * WPC, 256, 0, stream>>>(
        Whh[0], bhh[0], Whh[1], bhh[1], Whh[2], bhh[2], Whh[3], bhh[3],
        gi, hpk, ss);

    dense1_kernel<<<D_DIM / 4, 256, 0, stream>>>(d1w, d1b, hpk, h1, ss);
    dense2_kernel<<<1, 256, 0, stream>>>(d2w, d2b, h1, out);
}